// Round 6
// baseline (485.827 us; speedup 1.0000x reference)
//
#include <hip/hip_runtime.h>

// ---------------------------------------------------------------------------
// CausalAttention: B=8, S=2048, D=1024, fp32 in, fp32 out.
// Round 6: XCD/L2 locality swizzles + causal-waste elimination.
//   - GEMM grids put the M-strip on blockIdx.x (fastest) so consecutive
//     blocks (round-robin across XCDs) own DIFFERENT strips -> the heavy
//     shared tile (X-strip / Q-strip / P-strip) stays XCD-local.
//   - scores: no -inf fill (masked tiles exit w/o writes); raw epilogue.
//   - softmax: index-masked causal; skips masked loads/stores; zero-fills
//     only the (row, kcap) gap that pv reads.
//   - pv: by reversed (longest blocks first).
//   ws: Q 32 | K 32 | Vt 32 | Sc 64 MB (xh/Wh alias Sc head; dead by scores).
// ---------------------------------------------------------------------------

typedef _Float16 v8h __attribute__((ext_vector_type(8)));
typedef _Float16 v4h __attribute__((ext_vector_type(4)));
typedef float    v4f __attribute__((ext_vector_type(4)));

#define TM 128
#define TN 128
#define BK 64

__device__ __forceinline__ void async16(const _Float16* g, _Float16* l) {
  __builtin_amdgcn_global_load_lds(
      (__attribute__((address_space(1))) void*)(void*)g,
      (__attribute__((address_space(3))) void*)l, 16, 0, 0);
}

__device__ __forceinline__ void mfma_slab(const _Float16* As, const _Float16* Bs,
                                          int wr, int wc, int lr, int quad,
                                          v4f acc[4][4]) {
#pragma unroll
  for (int ks = 0; ks < 2; ++ks) {
    v8h a[4], b[4];
#pragma unroll
    for (int i = 0; i < 4; ++i) {
      a[i] = *(const v8h*)&As[(wr + i * 16 + lr) * BK + ks * 32 + quad * 8];
      b[i] = *(const v8h*)&Bs[(wc + i * 16 + lr) * BK + ks * 32 + quad * 8];
    }
#pragma unroll
    for (int i = 0; i < 4; ++i)
#pragma unroll
      for (int j = 0; j < 4; ++j)
        acc[i][j] = __builtin_amdgcn_mfma_f32_16x16x32_f16(a[i], b[j],
                                                           acc[i][j], 0, 0, 0);
  }
}

// fp32 -> fp16, 8 elems/thread.
__global__ __launch_bounds__(256)
void cvt_f16(const float* __restrict__ src, _Float16* __restrict__ dst) {
  const int i = (blockIdx.x * 256 + threadIdx.x) * 8;
  float4 a = *(const float4*)(src + i);
  float4 b = *(const float4*)(src + i + 4);
  v8h o = {(_Float16)a.x, (_Float16)a.y, (_Float16)a.z, (_Float16)a.w,
           (_Float16)b.x, (_Float16)b.y, (_Float16)b.z, (_Float16)b.w};
  *(v8h*)(dst + i) = o;
}

// Wq|Wk|Wv -> packed fp16 (blockIdx.y selects source).
__global__ __launch_bounds__(256)
void cvt_w3(const float* __restrict__ Wq, const float* __restrict__ Wk,
            const float* __restrict__ Wv, _Float16* __restrict__ dst) {
  const float* src = (blockIdx.y == 0) ? Wq : (blockIdx.y == 1) ? Wk : Wv;
  const int i = (blockIdx.x * 256 + threadIdx.x) * 8;
  float4 a = *(const float4*)(src + i);
  float4 b = *(const float4*)(src + i + 4);
  v8h o = {(_Float16)a.x, (_Float16)a.y, (_Float16)a.z, (_Float16)a.w,
           (_Float16)b.x, (_Float16)b.y, (_Float16)b.z, (_Float16)b.w};
  *(v8h*)(dst + (size_t)blockIdx.y * 1024 * 1024 + i) = o;
}

// ---------------------------------------------------------------------------
// Projection. Grid (128 m-strips [fastest], 24 n-tiles): m-strip is XCD-local.
// ---------------------------------------------------------------------------
__global__ __launch_bounds__(256)
void proj_gemm(const _Float16* __restrict__ X, const _Float16* __restrict__ W,
               _Float16* __restrict__ Qb, _Float16* __restrict__ Kb,
               _Float16* __restrict__ Vt) {
  const int tid = threadIdx.x;
  const int m0 = blockIdx.x * TM, n0 = blockIdx.y * TN;   // swizzled
  const int which = n0 >> 10;
  const int nw = n0 & 1023;

  __shared__ _Float16 As[TM * BK];
  __shared__ _Float16 Bs[TN * BK];

  const int lane = tid & 63, w = tid >> 6;
  const int wr = (w >> 1) * 64, wc = (w & 1) * 64;
  const int lr = lane & 15, quad = lane >> 4;

  v4f acc[4][4];
#pragma unroll
  for (int i = 0; i < 4; ++i)
#pragma unroll
    for (int j = 0; j < 4; ++j) acc[i][j] = (v4f){0.f, 0.f, 0.f, 0.f};

  for (int kt = 0; kt < 1024 / BK; ++kt) {
    const int k0 = kt * BK;
#pragma unroll
    for (int r = 0; r < 4; ++r) {
      const int c = w * 256 + r * 64 + lane;
      const int row = c >> 3, col = (c & 7) * 8;
      async16(X + (size_t)(m0 + row) * 1024 + k0 + col,
              As + (size_t)(w * 256 + r * 64) * 8);
      async16(W + (size_t)(n0 + row) * 1024 + k0 + col,
              Bs + (size_t)(w * 256 + r * 64) * 8);
    }
    __syncthreads();
    mfma_slab(As, Bs, wr, wc, lr, quad, acc);
    __syncthreads();
  }

#pragma unroll
  for (int i = 0; i < 4; ++i) {
    const int r0 = m0 + wr + i * 16 + quad * 4;
#pragma unroll
    for (int j = 0; j < 4; ++j) {
      const int cl = wc + j * 16 + lr;
      if (which < 2) {
        _Float16* dst = (which == 0) ? Qb : Kb;
        const int col = nw + cl;
#pragma unroll
        for (int rg = 0; rg < 4; ++rg)
          dst[(size_t)(r0 + rg) * 1024 + col] = (_Float16)acc[i][j][rg];
      } else {
        const int d = nw + cl;
        const int b = r0 >> 11, s = r0 & 2047;
        v4h o = {(_Float16)acc[i][j][0], (_Float16)acc[i][j][1],
                 (_Float16)acc[i][j][2], (_Float16)acc[i][j][3]};
        *(v4h*)(Vt + (size_t)b * 1024 * 2048 + (size_t)d * 2048 + s) = o;
      }
    }
  }
}

// ---------------------------------------------------------------------------
// Scores: raw QK^T, lower-triangle tiles only. Grid (16 by [fastest], 16 bx, 8 bz).
// Masked region is never written (softmax masks by index).
// ---------------------------------------------------------------------------
__global__ __launch_bounds__(256)
void scores_gemm(const _Float16* __restrict__ Q, const _Float16* __restrict__ K,
                 _Float16* __restrict__ Sc) {
  const int by = blockIdx.x, bx = blockIdx.y, bz = blockIdx.z;   // swizzled
  if (bx > by) return;                                           // no fill
  const int tid = threadIdx.x;
  const int n0 = bx * TN, m0 = by * TM;
  _Float16* Cb = Sc + (size_t)bz * 2048 * 2048;

  __shared__ _Float16 As[TM * BK];
  __shared__ _Float16 Bs[TN * BK];
  const _Float16* Qb = Q + (size_t)bz * 2048 * 1024;
  const _Float16* Kb = K + (size_t)bz * 2048 * 1024;

  const int lane = tid & 63, w = tid >> 6;
  const int wr = (w >> 1) * 64, wc = (w & 1) * 64;
  const int lr = lane & 15, quad = lane >> 4;

  v4f acc[4][4];
#pragma unroll
  for (int i = 0; i < 4; ++i)
#pragma unroll
    for (int j = 0; j < 4; ++j) acc[i][j] = (v4f){0.f, 0.f, 0.f, 0.f};

  for (int kt = 0; kt < 1024 / BK; ++kt) {
    const int k0 = kt * BK;
#pragma unroll
    for (int r = 0; r < 4; ++r) {
      const int c = w * 256 + r * 64 + lane;
      const int row = c >> 3, col = (c & 7) * 8;
      async16(Qb + (size_t)(m0 + row) * 1024 + k0 + col,
              As + (size_t)(w * 256 + r * 64) * 8);
      async16(Kb + (size_t)(n0 + row) * 1024 + k0 + col,
              Bs + (size_t)(w * 256 + r * 64) * 8);
    }
    __syncthreads();
    mfma_slab(As, Bs, wr, wc, lr, quad, acc);
    __syncthreads();
  }

#pragma unroll
  for (int i = 0; i < 4; ++i) {
    const int r0 = m0 + wr + i * 16 + quad * 4;
#pragma unroll
    for (int j = 0; j < 4; ++j) {
      const int cc = n0 + wc + j * 16 + lr;
#pragma unroll
      for (int rg = 0; rg < 4; ++rg)
        Cb[(size_t)(r0 + rg) * 2048 + cc] = (_Float16)acc[i][j][rg];  // raw
    }
  }
}

// ---------------------------------------------------------------------------
// Row softmax, index-masked causal. Writes P for k <= r, zeros for
// r < k < kcap (pv's read bound), nothing beyond kcap.
// ---------------------------------------------------------------------------
__global__ __launch_bounds__(256)
void softmax_rows(_Float16* __restrict__ Sc) {
  const int grow = blockIdx.x;                   // 0..16383
  const int r = grow & 2047;                     // row within batch
  _Float16* base = Sc + (size_t)grow * 2048;
  const int tid = threadIdx.x;
  const int lane = tid & 63, w = tid >> 6;
  const int k0 = tid * 8;
  const int kcap = ((r >> 7) + 1) * 128;         // pv reads k < kcap
  const float ninf = -__builtin_inff();

  float f[8];
  const bool any = (k0 <= r);
  if (any) {
    v8h pv = *(const v8h*)(base + k0);
#pragma unroll
    for (int j = 0; j < 8; ++j) f[j] = (k0 + j <= r) ? (float)pv[j] : ninf;
  } else {
#pragma unroll
    for (int j = 0; j < 8; ++j) f[j] = ninf;
  }

  float mx = f[0];
#pragma unroll
  for (int j = 1; j < 8; ++j) mx = fmaxf(mx, f[j]);
#pragma unroll
  for (int off = 32; off; off >>= 1) mx = fmaxf(mx, __shfl_xor(mx, off));
  __shared__ float redm[4], reds[4];
  if (lane == 0) redm[w] = mx;
  __syncthreads();
  mx = fmaxf(fmaxf(redm[0], redm[1]), fmaxf(redm[2], redm[3]));

  const float scale = 0.03125f;                  // 1/sqrt(1024)
  float e[8], s = 0.f;
#pragma unroll
  for (int j = 0; j < 8; ++j) {
    e[j] = (k0 + j <= r) ? __expf((f[j] - mx) * scale) : 0.f;
    s += e[j];
  }
#pragma unroll
  for (int off = 32; off; off >>= 1) s += __shfl_xor(s, off);
  if (lane == 0) reds[w] = s;
  __syncthreads();
  s = reds[0] + reds[1] + reds[2] + reds[3];
  const float inv = 1.0f / s;

  if (k0 < kcap) {
    v8h o;
#pragma unroll
    for (int j = 0; j < 8; ++j) o[j] = (_Float16)(e[j] * inv);
    *(v8h*)(base + k0) = o;
  }
}

// ---------------------------------------------------------------------------
// PV: out = P @ Vt, fp32 out. Grid (16 by [fastest, REVERSED], 8 bx, 8 bz).
// ---------------------------------------------------------------------------
__global__ __launch_bounds__(256)
void pv_gemm(const _Float16* __restrict__ P, const _Float16* __restrict__ Vt,
             float* __restrict__ Out) {
  const int tid = threadIdx.x;
  const int by = 15 - blockIdx.x;                // longest K-loops first
  const int bx = blockIdx.y, bz = blockIdx.z;
  const int n0 = bx * TN, m0 = by * TM;
  const _Float16* Pb = P + (size_t)bz * 2048 * 2048;
  const _Float16* Vb = Vt + (size_t)bz * 1024 * 2048;
  float* Cb = Out + (size_t)bz * 2048 * 1024;

  __shared__ _Float16 As[TM * BK];
  __shared__ _Float16 Bs[TN * BK];

  const int lane = tid & 63, w = tid >> 6;
  const int wr = (w >> 1) * 64, wc = (w & 1) * 64;
  const int lr = lane & 15, quad = lane >> 4;

  v4f acc[4][4];
#pragma unroll
  for (int i = 0; i < 4; ++i)
#pragma unroll
    for (int j = 0; j < 4; ++j) acc[i][j] = (v4f){0.f, 0.f, 0.f, 0.f};

  const int ksteps = (by + 1) * 2;
  for (int kt = 0; kt < ksteps; ++kt) {
    const int k0 = kt * BK;
#pragma unroll
    for (int r = 0; r < 4; ++r) {
      const int c = w * 256 + r * 64 + lane;
      const int row = c >> 3, col = (c & 7) * 8;
      async16(Pb + (size_t)(m0 + row) * 2048 + k0 + col,
              As + (size_t)(w * 256 + r * 64) * 8);
      async16(Vb + (size_t)(n0 + row) * 2048 + k0 + col,
              Bs + (size_t)(w * 256 + r * 64) * 8);
    }
    __syncthreads();
    mfma_slab(As, Bs, wr, wc, lr, quad, acc);
    __syncthreads();
  }

#pragma unroll
  for (int i = 0; i < 4; ++i) {
    const int r0 = m0 + wr + i * 16 + quad * 4;
#pragma unroll
    for (int j = 0; j < 4; ++j) {
      const int cc = n0 + wc + j * 16 + lr;
#pragma unroll
      for (int rg = 0; rg < 4; ++rg)
        Cb[(size_t)(r0 + rg) * 1024 + cc] = acc[i][j][rg];
    }
  }
}

// ---------------------------------------------------------------------------
extern "C" void kernel_launch(void* const* d_in, const int* in_sizes, int n_in,
                              void* d_out, int out_size, void* d_ws, size_t ws_size,
                              hipStream_t stream) {
  const int B = 8, S = 2048, D = 1024;
  const int M = B * S;
  const float* x  = (const float*)d_in[0];
  const float* Wq = (const float*)d_in[1];
  const float* Wk = (const float*)d_in[2];
  const float* Wv = (const float*)d_in[3];
  float* out = (float*)d_out;

  char* ws = (char*)d_ws;
  _Float16* Qb = (_Float16*)ws;                          // [M][1024]
  _Float16* Kb = (_Float16*)(ws + (size_t)33554432);     // [M][1024]
  _Float16* Vt = (_Float16*)(ws + (size_t)67108864);     // [B][1024][2048]
  _Float16* Sc = (_Float16*)(ws + (size_t)100663296);    // [B][2048][2048]
  _Float16* xh = Sc;                                     // alias (dead early)
  _Float16* Wh = Sc + (size_t)M * D;                     // alias

  cvt_f16<<<(M * D) / 2048, 256, 0, stream>>>(x, xh);
  cvt_w3<<<dim3((D * D) / 2048, 3), 256, 0, stream>>>(Wq, Wk, Wv, Wh);

  proj_gemm<<<dim3(M / TM, 24), 256, 0, stream>>>(xh, Wh, Qb, Kb, Vt);
  scores_gemm<<<dim3(S / TM, S / TN, B), 256, 0, stream>>>(Qb, Kb, Sc);
  softmax_rows<<<B * S, 256, 0, stream>>>(Sc);
  pv_gemm<<<dim3(S / TM, D / TN, B), 256, 0, stream>>>(Sc, Vt, out);
}

// Round 7
// 484.246 us; speedup vs baseline: 1.0033x; 1.0033x over previous
//
#include <hip/hip_runtime.h>

// ---------------------------------------------------------------------------
// CausalAttention: B=8, S=2048, D=1024, fp32 in, fp32 out.
// Round 7: instrumentation + targeted revert.
//   - proj split into 3 kernels (Q/K/V) so the attention-phase kernels
//     surface in rocprof top-5 (round 6's top-5 was all proj replicas).
//   - scores/pv grids reverted to round-5 dispatch order (bx fastest) —
//     round 6 changed three orders at once and net-regressed ~20 us.
//   - kept from round 6: scores writes only lower-triangle tiles (no -inf
//     fill), softmax masks causally BY INDEX and stores only k < kcap.
//   - single fused cvt kernel.
//   ws: Q 32 | K 32 | Vt 32 | Sc 64 MB (xh/Wh alias Sc head; dead by scores).
// ---------------------------------------------------------------------------

typedef _Float16 v8h __attribute__((ext_vector_type(8)));
typedef _Float16 v4h __attribute__((ext_vector_type(4)));
typedef float    v4f __attribute__((ext_vector_type(4)));

#define TM 128
#define TN 128
#define BK 64

__device__ __forceinline__ void async16(const _Float16* g, _Float16* l) {
  __builtin_amdgcn_global_load_lds(
      (__attribute__((address_space(1))) void*)(void*)g,
      (__attribute__((address_space(3))) void*)l, 16, 0, 0);
}

__device__ __forceinline__ void mfma_slab(const _Float16* As, const _Float16* Bs,
                                          int wr, int wc, int lr, int quad,
                                          v4f acc[4][4]) {
#pragma unroll
  for (int ks = 0; ks < 2; ++ks) {
    v8h a[4], b[4];
#pragma unroll
    for (int i = 0; i < 4; ++i) {
      a[i] = *(const v8h*)&As[(wr + i * 16 + lr) * BK + ks * 32 + quad * 8];
      b[i] = *(const v8h*)&Bs[(wc + i * 16 + lr) * BK + ks * 32 + quad * 8];
    }
#pragma unroll
    for (int i = 0; i < 4; ++i)
#pragma unroll
      for (int j = 0; j < 4; ++j)
        acc[i][j] = __builtin_amdgcn_mfma_f32_16x16x32_f16(a[i], b[j],
                                                           acc[i][j], 0, 0, 0);
  }
}

// ---------------------------------------------------------------------------
// Fused fp32->fp16 convert: blocks [0,8192) convert x, [8192,9728) convert W.
// ---------------------------------------------------------------------------
__global__ __launch_bounds__(256)
void cvt_all(const float* __restrict__ x, const float* __restrict__ Wq,
             const float* __restrict__ Wk, const float* __restrict__ Wv,
             _Float16* __restrict__ xh, _Float16* __restrict__ Wh) {
  const int blk = blockIdx.x;
  const float* src;
  _Float16* dst;
  int i;
  if (blk < 8192) {                       // x: 16M elems
    src = x; dst = xh;
    i = blk * 2048 + threadIdx.x * 8;
  } else {                                // W: 3 x 1M elems
    const int idx = blk - 8192;
    const int which = idx >> 9;           // /512
    src = (which == 0) ? Wq : (which == 1) ? Wk : Wv;
    dst = Wh + (size_t)which * 1024 * 1024;
    i = (idx & 511) * 2048 + threadIdx.x * 8;
  }
  float4 a = *(const float4*)(src + i);
  float4 b = *(const float4*)(src + i + 4);
  v8h o = {(_Float16)a.x, (_Float16)a.y, (_Float16)a.z, (_Float16)a.w,
           (_Float16)b.x, (_Float16)b.y, (_Float16)b.z, (_Float16)b.w};
  *(v8h*)(dst + i) = o;
}

// ---------------------------------------------------------------------------
// One projection (Q, K, or V): C[m][n] = X[m][:] . W[n][:], W is this proj's
// [1024][1024] fp16. vt_mode=0: row store to dst[m][n]; vt_mode=1: transposed
// store Vt[b][d][s]. Grid (128 m-strips [fastest], 8 n-tiles).
// ---------------------------------------------------------------------------
__global__ __launch_bounds__(256)
void proj_one(const _Float16* __restrict__ X, const _Float16* __restrict__ W,
              _Float16* __restrict__ dst, int vt_mode) {
  const int tid = threadIdx.x;
  const int m0 = blockIdx.x * TM, n0 = blockIdx.y * TN;

  __shared__ _Float16 As[TM * BK];
  __shared__ _Float16 Bs[TN * BK];

  const int lane = tid & 63, w = tid >> 6;
  const int wr = (w >> 1) * 64, wc = (w & 1) * 64;
  const int lr = lane & 15, quad = lane >> 4;

  v4f acc[4][4];
#pragma unroll
  for (int i = 0; i < 4; ++i)
#pragma unroll
    for (int j = 0; j < 4; ++j) acc[i][j] = (v4f){0.f, 0.f, 0.f, 0.f};

  for (int kt = 0; kt < 1024 / BK; ++kt) {
    const int k0 = kt * BK;
#pragma unroll
    for (int r = 0; r < 4; ++r) {
      const int c = w * 256 + r * 64 + lane;
      const int row = c >> 3, col = (c & 7) * 8;
      async16(X + (size_t)(m0 + row) * 1024 + k0 + col,
              As + (size_t)(w * 256 + r * 64) * 8);
      async16(W + (size_t)(n0 + row) * 1024 + k0 + col,
              Bs + (size_t)(w * 256 + r * 64) * 8);
    }
    __syncthreads();
    mfma_slab(As, Bs, wr, wc, lr, quad, acc);
    __syncthreads();
  }

#pragma unroll
  for (int i = 0; i < 4; ++i) {
    const int r0 = m0 + wr + i * 16 + quad * 4;
#pragma unroll
    for (int j = 0; j < 4; ++j) {
      const int cl = n0 + wc + j * 16 + lr;
      if (vt_mode == 0) {
#pragma unroll
        for (int rg = 0; rg < 4; ++rg)
          dst[(size_t)(r0 + rg) * 1024 + cl] = (_Float16)acc[i][j][rg];
      } else {
        const int b = r0 >> 11, s = r0 & 2047;
        v4h o = {(_Float16)acc[i][j][0], (_Float16)acc[i][j][1],
                 (_Float16)acc[i][j][2], (_Float16)acc[i][j][3]};
        *(v4h*)(dst + (size_t)b * 1024 * 2048 + (size_t)cl * 2048 + s) = o;
      }
    }
  }
}

// ---------------------------------------------------------------------------
// Scores: raw QK^T, lower-triangle tiles only (no masked-tile writes).
// Grid (16 bx [fastest], 16 by, 8 bz) — round-5 order.
// ---------------------------------------------------------------------------
__global__ __launch_bounds__(256)
void scores_gemm(const _Float16* __restrict__ Q, const _Float16* __restrict__ K,
                 _Float16* __restrict__ Sc) {
  const int bx = blockIdx.x, by = blockIdx.y, bz = blockIdx.z;
  if (bx > by) return;
  const int tid = threadIdx.x;
  const int n0 = bx * TN, m0 = by * TM;
  _Float16* Cb = Sc + (size_t)bz * 2048 * 2048;

  __shared__ _Float16 As[TM * BK];
  __shared__ _Float16 Bs[TN * BK];
  const _Float16* Qb = Q + (size_t)bz * 2048 * 1024;
  const _Float16* Kb = K + (size_t)bz * 2048 * 1024;

  const int lane = tid & 63, w = tid >> 6;
  const int wr = (w >> 1) * 64, wc = (w & 1) * 64;
  const int lr = lane & 15, quad = lane >> 4;

  v4f acc[4][4];
#pragma unroll
  for (int i = 0; i < 4; ++i)
#pragma unroll
    for (int j = 0; j < 4; ++j) acc[i][j] = (v4f){0.f, 0.f, 0.f, 0.f};

  for (int kt = 0; kt < 1024 / BK; ++kt) {
    const int k0 = kt * BK;
#pragma unroll
    for (int r = 0; r < 4; ++r) {
      const int c = w * 256 + r * 64 + lane;
      const int row = c >> 3, col = (c & 7) * 8;
      async16(Qb + (size_t)(m0 + row) * 1024 + k0 + col,
              As + (size_t)(w * 256 + r * 64) * 8);
      async16(Kb + (size_t)(n0 + row) * 1024 + k0 + col,
              Bs + (size_t)(w * 256 + r * 64) * 8);
    }
    __syncthreads();
    mfma_slab(As, Bs, wr, wc, lr, quad, acc);
    __syncthreads();
  }

#pragma unroll
  for (int i = 0; i < 4; ++i) {
    const int r0 = m0 + wr + i * 16 + quad * 4;
#pragma unroll
    for (int j = 0; j < 4; ++j) {
      const int cc = n0 + wc + j * 16 + lr;
#pragma unroll
      for (int rg = 0; rg < 4; ++rg)
        Cb[(size_t)(r0 + rg) * 2048 + cc] = (_Float16)acc[i][j][rg];
    }
  }
}

// ---------------------------------------------------------------------------
// Row softmax, index-masked causal; stores P for k < kcap only (pv bound).
// ---------------------------------------------------------------------------
__global__ __launch_bounds__(256)
void softmax_rows(_Float16* __restrict__ Sc) {
  const int grow = blockIdx.x;
  const int r = grow & 2047;
  _Float16* base = Sc + (size_t)grow * 2048;
  const int tid = threadIdx.x;
  const int lane = tid & 63, w = tid >> 6;
  const int k0 = tid * 8;
  const int kcap = ((r >> 7) + 1) * 128;
  const float ninf = -__builtin_inff();

  float f[8];
  if (k0 <= r) {
    v8h pv = *(const v8h*)(base + k0);
#pragma unroll
    for (int j = 0; j < 8; ++j) f[j] = (k0 + j <= r) ? (float)pv[j] : ninf;
  } else {
#pragma unroll
    for (int j = 0; j < 8; ++j) f[j] = ninf;
  }

  float mx = f[0];
#pragma unroll
  for (int j = 1; j < 8; ++j) mx = fmaxf(mx, f[j]);
#pragma unroll
  for (int off = 32; off; off >>= 1) mx = fmaxf(mx, __shfl_xor(mx, off));
  __shared__ float redm[4], reds[4];
  if (lane == 0) redm[w] = mx;
  __syncthreads();
  mx = fmaxf(fmaxf(redm[0], redm[1]), fmaxf(redm[2], redm[3]));

  const float scale = 0.03125f;
  float e[8], s = 0.f;
#pragma unroll
  for (int j = 0; j < 8; ++j) {
    e[j] = (k0 + j <= r) ? __expf((f[j] - mx) * scale) : 0.f;
    s += e[j];
  }
#pragma unroll
  for (int off = 32; off; off >>= 1) s += __shfl_xor(s, off);
  if (lane == 0) reds[w] = s;
  __syncthreads();
  s = reds[0] + reds[1] + reds[2] + reds[3];
  const float inv = 1.0f / s;

  if (k0 < kcap) {
    v8h o;
#pragma unroll
    for (int j = 0; j < 8; ++j) o[j] = (_Float16)(e[j] * inv);
    *(v8h*)(base + k0) = o;
  }
}

// ---------------------------------------------------------------------------
// PV: out = P @ Vt, fp32 out, K-loop truncated to (by+1)*128.
// Grid (8 bx [fastest], 16 by, 8 bz) — round-5 order.
// ---------------------------------------------------------------------------
__global__ __launch_bounds__(256)
void pv_gemm(const _Float16* __restrict__ P, const _Float16* __restrict__ Vt,
             float* __restrict__ Out) {
  const int tid = threadIdx.x;
  const int bx = blockIdx.x, by = blockIdx.y, bz = blockIdx.z;
  const int n0 = bx * TN, m0 = by * TM;
  const _Float16* Pb = P + (size_t)bz * 2048 * 2048;
  const _Float16* Vb = Vt + (size_t)bz * 1024 * 2048;
  float* Cb = Out + (size_t)bz * 2048 * 1024;

  __shared__ _Float16 As[TM * BK];
  __shared__ _Float16 Bs[TN * BK];

  const int lane = tid & 63, w = tid >> 6;
  const int wr = (w >> 1) * 64, wc = (w & 1) * 64;
  const int lr = lane & 15, quad = lane >> 4;

  v4f acc[4][4];
#pragma unroll
  for (int i = 0; i < 4; ++i)
#pragma unroll
    for (int j = 0; j < 4; ++j) acc[i][j] = (v4f){0.f, 0.f, 0.f, 0.f};

  const int ksteps = (by + 1) * 2;
  for (int kt = 0; kt < ksteps; ++kt) {
    const int k0 = kt * BK;
#pragma unroll
    for (int r = 0; r < 4; ++r) {
      const int c = w * 256 + r * 64 + lane;
      const int row = c >> 3, col = (c & 7) * 8;
      async16(Pb + (size_t)(m0 + row) * 2048 + k0 + col,
              As + (size_t)(w * 256 + r * 64) * 8);
      async16(Vb + (size_t)(n0 + row) * 2048 + k0 + col,
              Bs + (size_t)(w * 256 + r * 64) * 8);
    }
    __syncthreads();
    mfma_slab(As, Bs, wr, wc, lr, quad, acc);
    __syncthreads();
  }

#pragma unroll
  for (int i = 0; i < 4; ++i) {
    const int r0 = m0 + wr + i * 16 + quad * 4;
#pragma unroll
    for (int j = 0; j < 4; ++j) {
      const int cc = n0 + wc + j * 16 + lr;
#pragma unroll
      for (int rg = 0; rg < 4; ++rg)
        Cb[(size_t)(r0 + rg) * 1024 + cc] = acc[i][j][rg];
    }
  }
}

// ---------------------------------------------------------------------------
extern "C" void kernel_launch(void* const* d_in, const int* in_sizes, int n_in,
                              void* d_out, int out_size, void* d_ws, size_t ws_size,
                              hipStream_t stream) {
  const int B = 8, S = 2048, D = 1024;
  const int M = B * S;
  const float* x  = (const float*)d_in[0];
  const float* Wq = (const float*)d_in[1];
  const float* Wk = (const float*)d_in[2];
  const float* Wv = (const float*)d_in[3];
  float* out = (float*)d_out;

  char* ws = (char*)d_ws;
  _Float16* Qb = (_Float16*)ws;                          // [M][1024]
  _Float16* Kb = (_Float16*)(ws + (size_t)33554432);     // [M][1024]
  _Float16* Vt = (_Float16*)(ws + (size_t)67108864);     // [B][1024][2048]
  _Float16* Sc = (_Float16*)(ws + (size_t)100663296);    // [B][2048][2048]
  _Float16* xh = Sc;                                     // alias (dead early)
  _Float16* Wh = Sc + (size_t)M * D;                     // alias

  cvt_all<<<9728, 256, 0, stream>>>(x, Wq, Wk, Wv, xh, Wh);

  proj_one<<<dim3(M / TM, 8), 256, 0, stream>>>(xh, Wh, Qb, 0);
  proj_one<<<dim3(M / TM, 8), 256, 0, stream>>>(
      xh, Wh + (size_t)1024 * 1024, Kb, 0);
  proj_one<<<dim3(M / TM, 8), 256, 0, stream>>>(
      xh, Wh + (size_t)2 * 1024 * 1024, Vt, 1);

  scores_gemm<<<dim3(S / TN, S / TM, B), 256, 0, stream>>>(Qb, Kb, Sc);
  softmax_rows<<<B * S, 256, 0, stream>>>(Sc);
  pv_gemm<<<dim3(D / TN, S / TM, B), 256, 0, stream>>>(Sc, Vt, out);
}